// Round 1
// baseline (934.659 us; speedup 1.0000x reference)
//
#include <hip/hip_runtime.h>
#include <math.h>

#define D_MODEL 1024
#define D_FF    4096
#define RANK    8
#define BATCH   4
#define SEQ     2048
#define MTOT    (BATCH*SEQ)
#define NHEADS  16
#define HDIM    64

typedef __attribute__((ext_vector_type(8))) __bf16 bf16x8;
typedef __attribute__((ext_vector_type(4))) float f32x4;
typedef __attribute__((ext_vector_type(8))) unsigned short u16x8;
typedef __attribute__((ext_vector_type(4))) unsigned short u16x4;

__device__ __forceinline__ unsigned short f2bf(float f) {
  union { float f; unsigned int u; } v; v.f = f;
  unsigned int u = v.u;
  u += 0x7fffu + ((u >> 16) & 1u);
  return (unsigned short)(u >> 16);
}
__device__ __forceinline__ float bf2f(unsigned short h) {
  union { unsigned int u; float f; } v; v.u = ((unsigned int)h) << 16;
  return v.f;
}

__device__ __forceinline__ f32x4 mfma16(bf16x8 a, bf16x8 b, f32x4 c) {
  return __builtin_amdgcn_mfma_f32_16x16x32_bf16(a, b, c, 0, 0, 0);
}

#define GLDS(g, l) __builtin_amdgcn_global_load_lds( \
    (const __attribute__((address_space(1))) void*)(g), \
    (__attribute__((address_space(3))) void*)(l), 16, 0, 0)

// ---------------------------------------------------------------- convert f32 -> bf16
__global__ __launch_bounds__(256) void cvt_bf16(const float* __restrict__ in,
                                                unsigned short* __restrict__ out, int n8)
{
  int i = blockIdx.x * 256 + threadIdx.x;
  if (i >= n8) return;
  const float4 a  = *reinterpret_cast<const float4*>(in + (size_t)i * 8);
  const float4 b  = *reinterpret_cast<const float4*>(in + (size_t)i * 8 + 4);
  u16x8 o;
  o[0] = f2bf(a.x); o[1] = f2bf(a.y); o[2] = f2bf(a.z); o[3] = f2bf(a.w);
  o[4] = f2bf(b.x); o[5] = f2bf(b.y); o[6] = f2bf(b.z); o[7] = f2bf(b.w);
  *reinterpret_cast<u16x8*>(out + (size_t)i * 8) = o;
}

// ---------------------------------------------------------------- layernorm (fp32 in, bf16 out)
__global__ __launch_bounds__(256) void ln_fwd(const float* __restrict__ x,
                                              const float* __restrict__ g,
                                              const float* __restrict__ be,
                                              unsigned short* __restrict__ out)
{
  const int row = blockIdx.x;
  const int t = threadIdx.x;
  const float* xr = x + (size_t)row * D_MODEL;
  float4 vv = *reinterpret_cast<const float4*>(xr + t * 4);
  float s  = vv.x + vv.y + vv.z + vv.w;
  float s2 = vv.x * vv.x + vv.y * vv.y + vv.z * vv.z + vv.w * vv.w;
#pragma unroll
  for (int mm = 1; mm < 64; mm <<= 1) { s += __shfl_xor(s, mm); s2 += __shfl_xor(s2, mm); }
  __shared__ float red[8];
  const int w = t >> 6, l = t & 63;
  if (l == 0) { red[w] = s; red[4 + w] = s2; }
  __syncthreads();
  s  = red[0] + red[1] + red[2] + red[3];
  s2 = red[4] + red[5] + red[6] + red[7];
  float mean = s * (1.f / D_MODEL);
  float var  = s2 * (1.f / D_MODEL) - mean * mean;
  float rstd = rsqrtf(var + 1e-5f);
  float4 gv = *reinterpret_cast<const float4*>(g  + t * 4);
  float4 bv = *reinterpret_cast<const float4*>(be + t * 4);
  u16x4 o;
  o[0] = f2bf((vv.x - mean) * rstd * gv.x + bv.x);
  o[1] = f2bf((vv.y - mean) * rstd * gv.y + bv.y);
  o[2] = f2bf((vv.z - mean) * rstd * gv.z + bv.z);
  o[3] = f2bf((vv.w - mean) * rstd * gv.w + bv.w);
  *reinterpret_cast<u16x4*>(out + (size_t)row * D_MODEL + t * 4) = o;
}

// ---------------------------------------------------------------- u[m][r] = sum_i h[m][i]*dyn[b][r][i]
template<int ILEN>
__global__ __launch_bounds__(256) void dyn_u(const unsigned short* __restrict__ hmat,
                                             const float* __restrict__ dyn,
                                             float* __restrict__ u)
{
  const int tid = threadIdx.x, w = tid >> 6, l = tid & 63;
  const int m0 = blockIdx.x * 16 + w * 4;
  const int b = m0 / SEQ;
  const float* dynb = dyn + (size_t)b * RANK * ILEN;
  float acc[4][RANK] = {};
  for (int s = 0; s < ILEN / 64; ++s) {
    const int i = l + s * 64;
    float hv[4];
#pragma unroll
    for (int rr = 0; rr < 4; ++rr) hv[rr] = bf2f(hmat[(size_t)(m0 + rr) * ILEN + i]);
#pragma unroll
    for (int r = 0; r < RANK; ++r) {
      float d = dynb[(size_t)r * ILEN + i];
#pragma unroll
      for (int rr = 0; rr < 4; ++rr) acc[rr][r] += hv[rr] * d;
    }
  }
#pragma unroll
  for (int rr = 0; rr < 4; ++rr)
#pragma unroll
    for (int r = 0; r < RANK; ++r) {
      float a = acc[rr][r];
#pragma unroll
      for (int mm = 1; mm < 64; mm <<= 1) a += __shfl_xor(a, mm);
      if (l == 0) u[(size_t)(m0 + rr) * RANK + r] = a;
    }
}

// ---------------------------------------------------------------- GEMM  C[m,n] = sum_k A[m,k]*B[n,k] (+epilogue)
// MODE 0: +dyn delta, bf16 out (QKV)
// MODE 1: +resid(fp32), fp32 out (Wo)
// MODE 2: +dyn delta +bias, gelu, bf16 out (FF1)
// MODE 3: +dyn delta +bias +resid, fp32 out (FF2)
template<int NDIM, int KDIM, int MODE>
__global__ __launch_bounds__(256) void gemm_bt(const unsigned short* __restrict__ A,
                                               const unsigned short* __restrict__ B,
                                               void* __restrict__ outp,
                                               const float* __restrict__ uvec,
                                               const float* __restrict__ Adyn,
                                               const float* __restrict__ bias,
                                               const float* __restrict__ resid)
{
  __shared__ unsigned short sA[128 * 32];
  __shared__ unsigned short sB[128 * 32];
  const int tid = threadIdx.x;
  const int w = tid >> 6, l = tid & 63;
  const int tm = blockIdx.y * 128, tn = blockIdx.x * 128;
  const int wr = w >> 1, wc = w & 1;

  f32x4 acc[4][4] = {};

  const unsigned short* Ag = A + (size_t)(tm + (tid >> 2)) * KDIM + (tid & 3) * 8;
  const unsigned short* Bg = B + (size_t)(tn + (tid >> 2)) * KDIM + (tid & 3) * 8;
  unsigned short* sAw0 = sA + w * 512;
  unsigned short* sAw1 = sA + 2048 + w * 512;
  unsigned short* sBw0 = sB + w * 512;
  unsigned short* sBw1 = sB + 2048 + w * 512;

  const int arow = wr * 64 + (l & 15);
  const int bcol = wc * 64 + (l & 15);
  const int koff = (l >> 4) * 8;

  for (int kt = 0; kt < KDIM; kt += 32) {
    __syncthreads();
    GLDS(Ag + kt, sAw0);
    GLDS(Ag + (size_t)64 * KDIM + kt, sAw1);
    GLDS(Bg + kt, sBw0);
    GLDS(Bg + (size_t)64 * KDIM + kt, sBw1);
    asm volatile("s_waitcnt vmcnt(0)" ::: "memory");
    __syncthreads();

    bf16x8 af[4], bfv[4];
#pragma unroll
    for (int i = 0; i < 4; ++i)
      af[i] = *reinterpret_cast<const bf16x8*>(&sA[(arow + i * 16) * 32 + koff]);
#pragma unroll
    for (int j = 0; j < 4; ++j)
      bfv[j] = *reinterpret_cast<const bf16x8*>(&sB[(bcol + j * 16) * 32 + koff]);
#pragma unroll
    for (int i = 0; i < 4; ++i)
#pragma unroll
      for (int j = 0; j < 4; ++j)
        acc[i][j] = mfma16(af[i], bfv[j], acc[i][j]);
  }

  const int rbase = tm + wr * 64 + ((l >> 4) << 2);
  const int cbase = tn + wc * 64 + (l & 15);
#pragma unroll
  for (int i = 0; i < 4; ++i) {
    float uu[4][8];
    if constexpr (MODE == 0 || MODE == 2 || MODE == 3) {
#pragma unroll
      for (int r = 0; r < 4; ++r) {
        const float* up = uvec + (size_t)(rbase + i * 16 + r) * RANK;
#pragma unroll
        for (int p = 0; p < 8; ++p) uu[r][p] = up[p];
      }
    }
#pragma unroll
    for (int j = 0; j < 4; ++j) {
      const int col = cbase + j * 16;
      float ad[8];
      if constexpr (MODE == 0 || MODE == 2 || MODE == 3) {
#pragma unroll
        for (int p = 0; p < 8; ++p) ad[p] = Adyn[(size_t)col * RANK + p];
      }
#pragma unroll
      for (int r = 0; r < 4; ++r) {
        const int row = rbase + i * 16 + r;
        float v = acc[i][j][r];
        if constexpr (MODE == 0 || MODE == 2 || MODE == 3) {
#pragma unroll
          for (int p = 0; p < 8; ++p) v += uu[r][p] * ad[p];
        }
        if constexpr (MODE == 2) {
          v += bias[col];
          v = 0.5f * v * (1.f + erff(v * 0.70710678118654752f));
        }
        if constexpr (MODE == 1) {
          v += resid[(size_t)row * NDIM + col];
        }
        if constexpr (MODE == 3) {
          v += bias[col] + resid[(size_t)row * NDIM + col];
        }
        if constexpr (MODE == 0 || MODE == 2) {
          ((unsigned short*)outp)[(size_t)row * NDIM + col] = f2bf(v);
        } else {
          ((float*)outp)[(size_t)row * NDIM + col] = v;
        }
      }
    }
  }
}

// ---------------------------------------------------------------- flash attention (non-causal)
__global__ __launch_bounds__(256) void attn_fwd(const unsigned short* __restrict__ q,
                                                const unsigned short* __restrict__ k,
                                                const unsigned short* __restrict__ v,
                                                unsigned short* __restrict__ ctx)
{
  __shared__ unsigned short sK[64 * 64];
  __shared__ unsigned short sVt[64 * 64];
  __shared__ unsigned short sP[4][32 * 64];

  const int tid = threadIdx.x, w = tid >> 6, l = tid & 63;
  const int bh = blockIdx.y, b = bh >> 4, hh = bh & 15;
  const int q0 = blockIdx.x * 128 + w * 32;
  const size_t base = ((size_t)b * SEQ) * D_MODEL + hh * HDIM;

  bf16x8 qf[2][2];
#pragma unroll
  for (int i = 0; i < 2; ++i)
#pragma unroll
    for (int ks = 0; ks < 2; ++ks)
      qf[i][ks] = *reinterpret_cast<const bf16x8*>(
          &q[base + (size_t)(q0 + i * 16 + (l & 15)) * D_MODEL + ks * 32 + (l >> 4) * 8]);

  float mrun[2][4], lrun[2][4];
  f32x4 oacc[2][4] = {};
#pragma unroll
  for (int i = 0; i < 2; ++i)
#pragma unroll
    for (int r = 0; r < 4; ++r) { mrun[i][r] = -3.0e38f; lrun[i][r] = 0.f; }

  const unsigned short* kg = k + base + (size_t)(tid >> 3) * D_MODEL + (tid & 7) * 8;
  unsigned short* sKw0 = sK + w * 512;
  unsigned short* sKw1 = sK + 2048 + w * 512;

  for (int kt = 0; kt < SEQ; kt += 64) {
    __syncthreads();
    GLDS(kg + (size_t)kt * D_MODEL, sKw0);
    GLDS(kg + (size_t)(kt + 32) * D_MODEL, sKw1);
#pragma unroll
    for (int s = 0; s < 2; ++s) {
      int key = s * 32 + (tid >> 3);
      int d0 = (tid & 7) * 8;
      u16x8 vv = *reinterpret_cast<const u16x8*>(&v[base + (size_t)(kt + key) * D_MODEL + d0]);
#pragma unroll
      for (int e = 0; e < 8; ++e) sVt[(d0 + e) * 64 + key] = vv[e];
    }
    asm volatile("s_waitcnt vmcnt(0)" ::: "memory");
    __syncthreads();

    // S = Q K^T
    f32x4 sacc[2][4] = {};
#pragma unroll
    for (int ks = 0; ks < 2; ++ks) {
#pragma unroll
      for (int j = 0; j < 4; ++j) {
        bf16x8 kf = *reinterpret_cast<const bf16x8*>(
            &sK[(j * 16 + (l & 15)) * 64 + ks * 32 + (l >> 4) * 8]);
#pragma unroll
        for (int i = 0; i < 2; ++i) sacc[i][j] = mfma16(qf[i][ks], kf, sacc[i][j]);
      }
    }

    // online softmax, P -> per-wave LDS (bf16)
#pragma unroll
    for (int i = 0; i < 2; ++i) {
#pragma unroll
      for (int r = 0; r < 4; ++r) {
        float s0 = sacc[i][0][r] * 0.125f;
        float s1 = sacc[i][1][r] * 0.125f;
        float s2 = sacc[i][2][r] * 0.125f;
        float s3 = sacc[i][3][r] * 0.125f;
        float mx = fmaxf(fmaxf(s0, s1), fmaxf(s2, s3));
#pragma unroll
        for (int mm = 1; mm < 16; mm <<= 1) mx = fmaxf(mx, __shfl_xor(mx, mm, 16));
        float mnew = fmaxf(mrun[i][r], mx);
        float alpha = __expf(mrun[i][r] - mnew);
        mrun[i][r] = mnew;
        float p0 = __expf(s0 - mnew), p1 = __expf(s1 - mnew);
        float p2 = __expf(s2 - mnew), p3 = __expf(s3 - mnew);
        float ps = p0 + p1 + p2 + p3;
#pragma unroll
        for (int mm = 1; mm < 16; mm <<= 1) ps += __shfl_xor(ps, mm, 16);
        lrun[i][r] = lrun[i][r] * alpha + ps;
        const int prow = i * 16 + ((l >> 4) << 2) + r;
        unsigned short* pp = &sP[w][prow * 64 + (l & 15)];
        pp[0] = f2bf(p0); pp[16] = f2bf(p1); pp[32] = f2bf(p2); pp[48] = f2bf(p3);
#pragma unroll
        for (int j = 0; j < 4; ++j) oacc[i][j][r] *= alpha;
      }
    }

    // O += P V
#pragma unroll
    for (int ks = 0; ks < 2; ++ks) {
      bf16x8 pf[2];
#pragma unroll
      for (int i = 0; i < 2; ++i)
        pf[i] = *reinterpret_cast<const bf16x8*>(
            &sP[w][(i * 16 + (l & 15)) * 64 + ks * 32 + (l >> 4) * 8]);
#pragma unroll
      for (int j = 0; j < 4; ++j) {
        bf16x8 vf = *reinterpret_cast<const bf16x8*>(
            &sVt[(j * 16 + (l & 15)) * 64 + ks * 32 + (l >> 4) * 8]);
#pragma unroll
        for (int i = 0; i < 2; ++i) oacc[i][j] = mfma16(pf[i], vf, oacc[i][j]);
      }
    }
  }

#pragma unroll
  for (int i = 0; i < 2; ++i)
#pragma unroll
    for (int r = 0; r < 4; ++r) {
      float inv = 1.f / lrun[i][r];
      int row = q0 + i * 16 + ((l >> 4) << 2) + r;
#pragma unroll
      for (int j = 0; j < 4; ++j)
        ctx[base + (size_t)row * D_MODEL + j * 16 + (l & 15)] = f2bf(oacc[i][j][r] * inv);
    }
}

// ---------------------------------------------------------------- launch
extern "C" void kernel_launch(void* const* d_in, const int* in_sizes, int n_in,
                              void* d_out, int out_size, void* d_ws, size_t ws_size,
                              hipStream_t stream)
{
  (void)in_sizes; (void)n_in; (void)out_size; (void)ws_size;
  const float* x      = (const float*)d_in[0];
  const float* dyn_q  = (const float*)d_in[1];
  const float* dyn_k  = (const float*)d_in[2];
  const float* dyn_v  = (const float*)d_in[3];
  const float* dyn_f1 = (const float*)d_in[4];
  const float* dyn_f2 = (const float*)d_in[5];
  const float* Wq = (const float*)d_in[6];
  const float* Aq = (const float*)d_in[7];
  const float* Wk = (const float*)d_in[8];
  const float* Ak = (const float*)d_in[9];
  const float* Wv = (const float*)d_in[10];
  const float* Av = (const float*)d_in[11];
  const float* Wo = (const float*)d_in[12];
  const float* W1 = (const float*)d_in[13];
  const float* b1 = (const float*)d_in[14];
  const float* A1 = (const float*)d_in[15];
  const float* W2 = (const float*)d_in[16];
  const float* b2 = (const float*)d_in[17];
  const float* A2 = (const float*)d_in[18];
  const float* g1 = (const float*)d_in[19];
  const float* be1 = (const float*)d_in[20];
  const float* g2 = (const float*)d_in[21];
  const float* be2 = (const float*)d_in[22];

  char* ws = (char*)d_ws;
  size_t o = 0;
  auto take = [&](size_t b) { size_t r = o; o += (b + 255) & ~(size_t)255; return r; };
  const size_t o_wq = take((size_t)D_MODEL * D_MODEL * 2);
  const size_t o_wk = take((size_t)D_MODEL * D_MODEL * 2);
  const size_t o_wv = take((size_t)D_MODEL * D_MODEL * 2);
  const size_t o_wo = take((size_t)D_MODEL * D_MODEL * 2);
  const size_t o_w1 = take((size_t)D_FF * D_MODEL * 2);
  const size_t o_w2 = take((size_t)D_FF * D_MODEL * 2);
  const size_t o_h1 = take((size_t)MTOT * D_MODEL * 2);   // later reused as ctx
  const size_t o_q  = take((size_t)MTOT * D_MODEL * 2);   // later reused as x2 (with o_k)
  const size_t o_k  = take((size_t)MTOT * D_MODEL * 2);
  const size_t o_v  = take((size_t)MTOT * D_MODEL * 2);   // later reused as h2
  const size_t o_u  = take((size_t)MTOT * RANK * 4 * 3);  // u_q,u_k,u_v; later u_ff1/u_ff2
  const size_t o_ff = take((size_t)MTOT * D_FF * 2);

  unsigned short* wq_b = (unsigned short*)(ws + o_wq);
  unsigned short* wk_b = (unsigned short*)(ws + o_wk);
  unsigned short* wv_b = (unsigned short*)(ws + o_wv);
  unsigned short* wo_b = (unsigned short*)(ws + o_wo);
  unsigned short* w1_b = (unsigned short*)(ws + o_w1);
  unsigned short* w2_b = (unsigned short*)(ws + o_w2);
  unsigned short* h1   = (unsigned short*)(ws + o_h1);
  unsigned short* qb   = (unsigned short*)(ws + o_q);
  unsigned short* kb   = (unsigned short*)(ws + o_k);
  unsigned short* vb   = (unsigned short*)(ws + o_v);
  float* u_q  = (float*)(ws + o_u);
  float* u_k  = u_q + (size_t)MTOT * RANK;
  float* u_v  = u_k + (size_t)MTOT * RANK;
  unsigned short* ctx = h1;                    // reuse
  float* x2 = (float*)(ws + o_q);              // reuse q+k (32MB)
  unsigned short* h2 = vb;                     // reuse
  float* u_f1 = u_q;                           // reuse
  float* u_f2 = u_k;                           // reuse
  unsigned short* ffb = (unsigned short*)(ws + o_ff);

  // 1. weights -> bf16
  cvt_bf16<<<512,  256, 0, stream>>>(Wq, wq_b, (D_MODEL * D_MODEL) / 8);
  cvt_bf16<<<512,  256, 0, stream>>>(Wk, wk_b, (D_MODEL * D_MODEL) / 8);
  cvt_bf16<<<512,  256, 0, stream>>>(Wv, wv_b, (D_MODEL * D_MODEL) / 8);
  cvt_bf16<<<512,  256, 0, stream>>>(Wo, wo_b, (D_MODEL * D_MODEL) / 8);
  cvt_bf16<<<2048, 256, 0, stream>>>(W1, w1_b, (D_FF * D_MODEL) / 8);
  cvt_bf16<<<2048, 256, 0, stream>>>(W2, w2_b, (D_FF * D_MODEL) / 8);

  // 2. LN1
  ln_fwd<<<MTOT, 256, 0, stream>>>(x, g1, be1, h1);

  // 3. dynamic u for q,k,v
  dyn_u<D_MODEL><<<MTOT / 16, 256, 0, stream>>>(h1, dyn_q, u_q);
  dyn_u<D_MODEL><<<MTOT / 16, 256, 0, stream>>>(h1, dyn_k, u_k);
  dyn_u<D_MODEL><<<MTOT / 16, 256, 0, stream>>>(h1, dyn_v, u_v);

  // 4. QKV projections
  dim3 gqkv(D_MODEL / 128, MTOT / 128);
  gemm_bt<D_MODEL, D_MODEL, 0><<<gqkv, 256, 0, stream>>>(h1, wq_b, qb, u_q, Aq, nullptr, nullptr);
  gemm_bt<D_MODEL, D_MODEL, 0><<<gqkv, 256, 0, stream>>>(h1, wk_b, kb, u_k, Ak, nullptr, nullptr);
  gemm_bt<D_MODEL, D_MODEL, 0><<<gqkv, 256, 0, stream>>>(h1, wv_b, vb, u_v, Av, nullptr, nullptr);

  // 5. attention
  attn_fwd<<<dim3(SEQ / 128, BATCH * NHEADS), 256, 0, stream>>>(qb, kb, vb, ctx);

  // 6. Wo + residual -> x2 (fp32)
  gemm_bt<D_MODEL, D_MODEL, 1><<<gqkv, 256, 0, stream>>>(ctx, wo_b, x2, nullptr, nullptr, nullptr, x);

  // 7. LN2
  ln_fwd<<<MTOT, 256, 0, stream>>>(x2, g2, be2, h2);

  // 8. u_ff1, FF1 (+bias,+delta,gelu) -> ff bf16
  dyn_u<D_MODEL><<<MTOT / 16, 256, 0, stream>>>(h2, dyn_f1, u_f1);
  gemm_bt<D_FF, D_MODEL, 2><<<dim3(D_FF / 128, MTOT / 128), 256, 0, stream>>>(
      h2, w1_b, ffb, u_f1, A1, b1, nullptr);

  // 9. u_ff2, FF2 (+bias,+delta,+resid) -> out fp32
  dyn_u<D_FF><<<MTOT / 16, 256, 0, stream>>>(ffb, dyn_f2, u_f2);
  gemm_bt<D_MODEL, D_FF, 3><<<gqkv, 256, 0, stream>>>(
      ffb, w2_b, (float*)d_out, u_f2, A2, b2, x2);
}

// Round 2
// 865.636 us; speedup vs baseline: 1.0797x; 1.0797x over previous
//
#include <hip/hip_runtime.h>
#include <math.h>

#define D_MODEL 1024
#define D_FF    4096
#define RANK    8
#define BATCH   4
#define SEQ     2048
#define MTOT    (BATCH*SEQ)
#define NHEADS  16
#define HDIM    64

typedef __attribute__((ext_vector_type(8))) __bf16 bf16x8;
typedef __attribute__((ext_vector_type(4))) float f32x4;
typedef __attribute__((ext_vector_type(8))) unsigned short u16x8;
typedef __attribute__((ext_vector_type(4))) unsigned short u16x4;

__device__ __forceinline__ unsigned short f2bf(float f) {
  union { float f; unsigned int u; } v; v.f = f;
  unsigned int u = v.u;
  u += 0x7fffu + ((u >> 16) & 1u);
  return (unsigned short)(u >> 16);
}
__device__ __forceinline__ float bf2f(unsigned short h) {
  union { unsigned int u; float f; } v; v.u = ((unsigned int)h) << 16;
  return v.f;
}

__device__ __forceinline__ f32x4 mfma16(bf16x8 a, bf16x8 b, f32x4 c) {
  return __builtin_amdgcn_mfma_f32_16x16x32_bf16(a, b, c, 0, 0, 0);
}

#define GLDS(g, l) __builtin_amdgcn_global_load_lds( \
    (const __attribute__((address_space(1))) void*)(g), \
    (__attribute__((address_space(3))) void*)(l), 16, 0, 0)

// ---------------------------------------------------------------- convert f32 -> bf16
__global__ __launch_bounds__(256) void cvt_bf16(const float* __restrict__ in,
                                                unsigned short* __restrict__ out, int n8)
{
  int i = blockIdx.x * 256 + threadIdx.x;
  if (i >= n8) return;
  const float4 a  = *reinterpret_cast<const float4*>(in + (size_t)i * 8);
  const float4 b  = *reinterpret_cast<const float4*>(in + (size_t)i * 8 + 4);
  u16x8 o;
  o[0] = f2bf(a.x); o[1] = f2bf(a.y); o[2] = f2bf(a.z); o[3] = f2bf(a.w);
  o[4] = f2bf(b.x); o[5] = f2bf(b.y); o[6] = f2bf(b.z); o[7] = f2bf(b.w);
  *reinterpret_cast<u16x8*>(out + (size_t)i * 8) = o;
}

// ---------------------------------------------------------------- layernorm (fp32 in, bf16 out)
__global__ __launch_bounds__(256) void ln_fwd(const float* __restrict__ x,
                                              const float* __restrict__ g,
                                              const float* __restrict__ be,
                                              unsigned short* __restrict__ out)
{
  const int row = blockIdx.x;
  const int t = threadIdx.x;
  const float* xr = x + (size_t)row * D_MODEL;
  float4 vv = *reinterpret_cast<const float4*>(xr + t * 4);
  float s  = vv.x + vv.y + vv.z + vv.w;
  float s2 = vv.x * vv.x + vv.y * vv.y + vv.z * vv.z + vv.w * vv.w;
#pragma unroll
  for (int mm = 1; mm < 64; mm <<= 1) { s += __shfl_xor(s, mm); s2 += __shfl_xor(s2, mm); }
  __shared__ float red[8];
  const int w = t >> 6, l = t & 63;
  if (l == 0) { red[w] = s; red[4 + w] = s2; }
  __syncthreads();
  s  = red[0] + red[1] + red[2] + red[3];
  s2 = red[4] + red[5] + red[6] + red[7];
  float mean = s * (1.f / D_MODEL);
  float var  = s2 * (1.f / D_MODEL) - mean * mean;
  float rstd = rsqrtf(var + 1e-5f);
  float4 gv = *reinterpret_cast<const float4*>(g  + t * 4);
  float4 bv = *reinterpret_cast<const float4*>(be + t * 4);
  u16x4 o;
  o[0] = f2bf((vv.x - mean) * rstd * gv.x + bv.x);
  o[1] = f2bf((vv.y - mean) * rstd * gv.y + bv.y);
  o[2] = f2bf((vv.z - mean) * rstd * gv.z + bv.z);
  o[3] = f2bf((vv.w - mean) * rstd * gv.w + bv.w);
  *reinterpret_cast<u16x4*>(out + (size_t)row * D_MODEL + t * 4) = o;
}

// ---------------------------------------------------------------- u[m][r] = sum_i h[m][i]*dyn[b][r][i]
template<int ILEN>
__global__ __launch_bounds__(256) void dyn_u(const unsigned short* __restrict__ hmat,
                                             const float* __restrict__ dyn,
                                             float* __restrict__ u)
{
  const int tid = threadIdx.x, w = tid >> 6, l = tid & 63;
  const int m0 = blockIdx.x * 16 + w * 4;
  const int b = m0 / SEQ;
  const float* dynb = dyn + (size_t)b * RANK * ILEN;
  float acc[4][RANK] = {};
  for (int s = 0; s < ILEN / 64; ++s) {
    const int i = l + s * 64;
    float hv[4];
#pragma unroll
    for (int rr = 0; rr < 4; ++rr) hv[rr] = bf2f(hmat[(size_t)(m0 + rr) * ILEN + i]);
#pragma unroll
    for (int r = 0; r < RANK; ++r) {
      float d = dynb[(size_t)r * ILEN + i];
#pragma unroll
      for (int rr = 0; rr < 4; ++rr) acc[rr][r] += hv[rr] * d;
    }
  }
#pragma unroll
  for (int rr = 0; rr < 4; ++rr)
#pragma unroll
    for (int r = 0; r < RANK; ++r) {
      float a = acc[rr][r];
#pragma unroll
      for (int mm = 1; mm < 64; mm <<= 1) a += __shfl_xor(a, mm);
      if (l == 0) u[(size_t)(m0 + rr) * RANK + r] = a;
    }
}

// ---------------------------------------------------------------- GEMM  C[m,n] = sum_k A[m,k]*B[n,k] (+epilogue)
// MODE 0: +dyn delta, bf16 out (Q,K)
// MODE 1: +resid(fp32), fp32 out (Wo)
// MODE 2: +dyn delta +bias, gelu, bf16 out (FF1)
// MODE 3: +dyn delta +bias +resid, fp32 out (FF2)
// MODE 4: +dyn delta, bf16 out TRANSPOSED as vt[b][h][d][t] (V)
template<int NDIM, int KDIM, int MODE>
__global__ __launch_bounds__(256) void gemm_bt(const unsigned short* __restrict__ A,
                                               const unsigned short* __restrict__ B,
                                               void* __restrict__ outp,
                                               const float* __restrict__ uvec,
                                               const float* __restrict__ Adyn,
                                               const float* __restrict__ bias,
                                               const float* __restrict__ resid)
{
  constexpr bool HAS_DYN = (MODE == 0 || MODE == 2 || MODE == 3 || MODE == 4);
  __shared__ unsigned short sA[128 * 32];
  __shared__ unsigned short sB[128 * 32];
  const int tid = threadIdx.x;
  const int w = tid >> 6, l = tid & 63;

  // bijective XCD swizzle (grids here are always a multiple of 8 blocks)
  constexpr int NBX = NDIM / 128;
  constexpr int NWG = NBX * (MTOT / 128);
  const int bid = blockIdx.y * NBX + blockIdx.x;
  const int sbid = (bid & 7) * (NWG / 8) + (bid >> 3);
  const int tm = (sbid / NBX) * 128, tn = (sbid % NBX) * 128;
  const int wr = w >> 1, wc = w & 1;

  f32x4 acc[4][4] = {};

  const unsigned short* Ag = A + (size_t)(tm + (tid >> 2)) * KDIM + (tid & 3) * 8;
  const unsigned short* Bg = B + (size_t)(tn + (tid >> 2)) * KDIM + (tid & 3) * 8;
  unsigned short* sAw0 = sA + w * 512;
  unsigned short* sAw1 = sA + 2048 + w * 512;
  unsigned short* sBw0 = sB + w * 512;
  unsigned short* sBw1 = sB + 2048 + w * 512;

  const int arow = wr * 64 + (l & 15);
  const int bcol = wc * 64 + (l & 15);
  const int koff = (l >> 4) * 8;

  for (int kt = 0; kt < KDIM; kt += 32) {
    __syncthreads();
    GLDS(Ag + kt, sAw0);
    GLDS(Ag + (size_t)64 * KDIM + kt, sAw1);
    GLDS(Bg + kt, sBw0);
    GLDS(Bg + (size_t)64 * KDIM + kt, sBw1);
    asm volatile("s_waitcnt vmcnt(0)" ::: "memory");
    __syncthreads();

    bf16x8 af[4], bfv[4];
#pragma unroll
    for (int i = 0; i < 4; ++i)
      af[i] = *reinterpret_cast<const bf16x8*>(&sA[(arow + i * 16) * 32 + koff]);
#pragma unroll
    for (int j = 0; j < 4; ++j)
      bfv[j] = *reinterpret_cast<const bf16x8*>(&sB[(bcol + j * 16) * 32 + koff]);
#pragma unroll
    for (int i = 0; i < 4; ++i)
#pragma unroll
      for (int j = 0; j < 4; ++j)
        acc[i][j] = mfma16(af[i], bfv[j], acc[i][j]);
  }

  const int rbase = tm + wr * 64 + ((l >> 4) << 2);
  const int cbase = tn + wc * 64 + (l & 15);
#pragma unroll
  for (int i = 0; i < 4; ++i) {
    float uu[4][8];
    if constexpr (HAS_DYN) {
#pragma unroll
      for (int r = 0; r < 4; ++r) {
        const float* up = uvec + (size_t)(rbase + i * 16 + r) * RANK;
#pragma unroll
        for (int p = 0; p < 8; ++p) uu[r][p] = up[p];
      }
    }
#pragma unroll
    for (int j = 0; j < 4; ++j) {
      const int col = cbase + j * 16;
      float ad[8];
      if constexpr (HAS_DYN) {
#pragma unroll
        for (int p = 0; p < 8; ++p) ad[p] = Adyn[(size_t)col * RANK + p];
      }
      float vv4[4];
#pragma unroll
      for (int r = 0; r < 4; ++r) {
        const int row = rbase + i * 16 + r;
        float v = acc[i][j][r];
        if constexpr (HAS_DYN) {
#pragma unroll
          for (int p = 0; p < 8; ++p) v += uu[r][p] * ad[p];
        }
        if constexpr (MODE == 2) {
          v += bias[col];
          v = 0.5f * v * (1.f + erff(v * 0.70710678118654752f));
        }
        if constexpr (MODE == 1) {
          v += resid[(size_t)row * NDIM + col];
        }
        if constexpr (MODE == 3) {
          v += bias[col] + resid[(size_t)row * NDIM + col];
        }
        vv4[r] = v;
      }
      if constexpr (MODE == 0 || MODE == 2) {
#pragma unroll
        for (int r = 0; r < 4; ++r)
          ((unsigned short*)outp)[(size_t)(rbase + i * 16 + r) * NDIM + col] = f2bf(vv4[r]);
      } else if constexpr (MODE == 4) {
        // vt[b][h][d][t]; 4 consecutive t values -> one 8B store
        const int row0 = rbase + i * 16;              // multiple of 4
        const int bb = row0 >> 11, tt = row0 & (SEQ - 1);
        const int hh = col >> 6, dd = col & 63;
        u16x4 o;
        o[0] = f2bf(vv4[0]); o[1] = f2bf(vv4[1]); o[2] = f2bf(vv4[2]); o[3] = f2bf(vv4[3]);
        *reinterpret_cast<u16x4*>(
            &((unsigned short*)outp)[(((size_t)bb * NHEADS + hh) * HDIM + dd) * SEQ + tt]) = o;
      } else {
#pragma unroll
        for (int r = 0; r < 4; ++r)
          ((float*)outp)[(size_t)(rbase + i * 16 + r) * NDIM + col] = vv4[r];
      }
    }
  }
}

// ---------------------------------------------------------------- flash attention (non-causal)
// K from [b,t,heads*d] (row = key), V pre-transposed: vt[b][h][d][t].
// sK/sV/sP all XOR-swizzled at 8-element granularity to kill bank conflicts;
// global_load_lds writes linearly, so the swizzle is applied to the GLOBAL
// source address (m173 pattern) and to every LDS read.
__global__ __launch_bounds__(256) void attn_fwd(const unsigned short* __restrict__ q,
                                                const unsigned short* __restrict__ k,
                                                const unsigned short* __restrict__ vt,
                                                unsigned short* __restrict__ ctx)
{
  __shared__ unsigned short sK[64 * 64];
  __shared__ unsigned short sV[64 * 64];
  __shared__ unsigned short sP[4][32 * 64];

  const int tid = threadIdx.x, w = tid >> 6, l = tid & 63;
  const int bh = blockIdx.y, b = bh >> 4, hh = bh & 15;
  const int q0 = blockIdx.x * 128 + w * 32;
  const size_t base = ((size_t)b * SEQ) * D_MODEL + hh * HDIM;
  const size_t vtbase = (size_t)bh * HDIM * SEQ;

  bf16x8 qf[2][2];
#pragma unroll
  for (int i = 0; i < 2; ++i)
#pragma unroll
    for (int ks = 0; ks < 2; ++ks)
      qf[i][ks] = *reinterpret_cast<const bf16x8*>(
          &q[base + (size_t)(q0 + i * 16 + (l & 15)) * D_MODEL + ks * 32 + (l >> 4) * 8]);

  float mrun[2][4], lrun[2][4];
  f32x4 oacc[2][4] = {};
#pragma unroll
  for (int i = 0; i < 2; ++i)
#pragma unroll
    for (int r = 0; r < 4; ++r) { mrun[i][r] = -3.0e38f; lrun[i][r] = 0.f; }

  // staging: slot n = c*256+tid covers LDS row (n>>3), col-block (tid&7).
  // source col-block is XOR'd with row&7 (row&7 identical for both calls).
  const int srow = tid >> 3;
  const int scol = ((tid & 7) ^ (srow & 7)) * 8;
  const unsigned short* kg = k + base + (size_t)srow * D_MODEL + scol;
  const unsigned short* vg = vt + vtbase + (size_t)srow * SEQ + scol;
  unsigned short* dK0 = sK + w * 512;
  unsigned short* dK1 = sK + 2048 + w * 512;
  unsigned short* dV0 = sV + w * 512;
  unsigned short* dV1 = sV + 2048 + w * 512;

  for (int kt = 0; kt < SEQ; kt += 64) {
    __syncthreads();
    GLDS(kg + (size_t)kt * D_MODEL, dK0);
    GLDS(kg + (size_t)(kt + 32) * D_MODEL, dK1);
    GLDS(vg + kt, dV0);
    GLDS(vg + kt + (size_t)32 * SEQ, dV1);
    asm volatile("s_waitcnt vmcnt(0)" ::: "memory");
    __syncthreads();

    // S = Q K^T
    f32x4 sacc[2][4] = {};
#pragma unroll
    for (int ks = 0; ks < 2; ++ks) {
#pragma unroll
      for (int j = 0; j < 4; ++j) {
        const int row = j * 16 + (l & 15);
        bf16x8 kf = *reinterpret_cast<const bf16x8*>(
            &sK[row * 64 + (((ks * 4 + (l >> 4)) ^ (row & 7)) << 3)]);
#pragma unroll
        for (int i = 0; i < 2; ++i) sacc[i][j] = mfma16(qf[i][ks], kf, sacc[i][j]);
      }
    }

    // online softmax, P -> per-wave LDS (bf16, swizzled)
#pragma unroll
    for (int i = 0; i < 2; ++i) {
#pragma unroll
      for (int r = 0; r < 4; ++r) {
        float s0 = sacc[i][0][r] * 0.125f;
        float s1 = sacc[i][1][r] * 0.125f;
        float s2 = sacc[i][2][r] * 0.125f;
        float s3 = sacc[i][3][r] * 0.125f;
        float mx = fmaxf(fmaxf(s0, s1), fmaxf(s2, s3));
#pragma unroll
        for (int mm = 1; mm < 16; mm <<= 1) mx = fmaxf(mx, __shfl_xor(mx, mm, 16));
        float mnew = fmaxf(mrun[i][r], mx);
        float alpha = __expf(mrun[i][r] - mnew);
        mrun[i][r] = mnew;
        float p0 = __expf(s0 - mnew), p1 = __expf(s1 - mnew);
        float p2 = __expf(s2 - mnew), p3 = __expf(s3 - mnew);
        float ps = p0 + p1 + p2 + p3;
#pragma unroll
        for (int mm = 1; mm < 16; mm <<= 1) ps += __shfl_xor(ps, mm, 16);
        lrun[i][r] = lrun[i][r] * alpha + ps;
        const int prow = i * 16 + ((l >> 4) << 2) + r;
        const int pswz = prow & 7;
        unsigned short* pb = &sP[w][prow * 64];
        const int chi = (l & 15) >> 3, clo = l & 7;
        pb[(((0 + chi) ^ pswz) << 3) + clo] = f2bf(p0);
        pb[(((2 + chi) ^ pswz) << 3) + clo] = f2bf(p1);
        pb[(((4 + chi) ^ pswz) << 3) + clo] = f2bf(p2);
        pb[(((6 + chi) ^ pswz) << 3) + clo] = f2bf(p3);
#pragma unroll
        for (int j = 0; j < 4; ++j) oacc[i][j][r] *= alpha;
      }
    }

    // O += P V  (B operand = vt rows = d)
#pragma unroll
    for (int ks = 0; ks < 2; ++ks) {
      bf16x8 pf[2];
#pragma unroll
      for (int i = 0; i < 2; ++i) {
        const int prw = i * 16 + (l & 15);
        pf[i] = *reinterpret_cast<const bf16x8*>(
            &sP[w][prw * 64 + (((ks * 4 + (l >> 4)) ^ (prw & 7)) << 3)]);
      }
#pragma unroll
      for (int j = 0; j < 4; ++j) {
        const int row = j * 16 + (l & 15);
        bf16x8 vf = *reinterpret_cast<const bf16x8*>(
            &sV[row * 64 + (((ks * 4 + (l >> 4)) ^ (row & 7)) << 3)]);
#pragma unroll
        for (int i = 0; i < 2; ++i) oacc[i][j] = mfma16(pf[i], vf, oacc[i][j]);
      }
    }
  }

#pragma unroll
  for (int i = 0; i < 2; ++i)
#pragma unroll
    for (int r = 0; r < 4; ++r) {
      float inv = 1.f / lrun[i][r];
      int row = q0 + i * 16 + ((l >> 4) << 2) + r;
#pragma unroll
      for (int j = 0; j < 4; ++j)
        ctx[base + (size_t)row * D_MODEL + j * 16 + (l & 15)] = f2bf(oacc[i][j][r] * inv);
    }
}

// ---------------------------------------------------------------- launch
extern "C" void kernel_launch(void* const* d_in, const int* in_sizes, int n_in,
                              void* d_out, int out_size, void* d_ws, size_t ws_size,
                              hipStream_t stream)
{
  (void)in_sizes; (void)n_in; (void)out_size; (void)ws_size;
  const float* x      = (const float*)d_in[0];
  const float* dyn_q  = (const float*)d_in[1];
  const float* dyn_k  = (const float*)d_in[2];
  const float* dyn_v  = (const float*)d_in[3];
  const float* dyn_f1 = (const float*)d_in[4];
  const float* dyn_f2 = (const float*)d_in[5];
  const float* Wq = (const float*)d_in[6];
  const float* Aq = (const float*)d_in[7];
  const float* Wk = (const float*)d_in[8];
  const float* Ak = (const float*)d_in[9];
  const float* Wv = (const float*)d_in[10];
  const float* Av = (const float*)d_in[11];
  const float* Wo = (const float*)d_in[12];
  const float* W1 = (const float*)d_in[13];
  const float* b1 = (const float*)d_in[14];
  const float* A1 = (const float*)d_in[15];
  const float* W2 = (const float*)d_in[16];
  const float* b2 = (const float*)d_in[17];
  const float* A2 = (const float*)d_in[18];
  const float* g1 = (const float*)d_in[19];
  const float* be1 = (const float*)d_in[20];
  const float* g2 = (const float*)d_in[21];
  const float* be2 = (const float*)d_in[22];

  char* ws = (char*)d_ws;
  size_t o = 0;
  auto take = [&](size_t b) { size_t r = o; o += (b + 255) & ~(size_t)255; return r; };
  const size_t o_wq = take((size_t)D_MODEL * D_MODEL * 2);
  const size_t o_wk = take((size_t)D_MODEL * D_MODEL * 2);
  const size_t o_wv = take((size_t)D_MODEL * D_MODEL * 2);
  const size_t o_wo = take((size_t)D_MODEL * D_MODEL * 2);
  const size_t o_w1 = take((size_t)D_FF * D_MODEL * 2);
  const size_t o_w2 = take((size_t)D_FF * D_MODEL * 2);
  const size_t o_h1 = take((size_t)MTOT * D_MODEL * 2);   // later reused as ctx
  const size_t o_q  = take((size_t)MTOT * D_MODEL * 2);   // later reused as x2 (with o_k)
  const size_t o_k  = take((size_t)MTOT * D_MODEL * 2);
  const size_t o_v  = take((size_t)MTOT * D_MODEL * 2);   // vt; later reused as h2
  const size_t o_u  = take((size_t)MTOT * RANK * 4 * 3);  // u_q,u_k,u_v; later u_ff1/u_ff2
  const size_t o_ff = take((size_t)MTOT * D_FF * 2);

  unsigned short* wq_b = (unsigned short*)(ws + o_wq);
  unsigned short* wk_b = (unsigned short*)(ws + o_wk);
  unsigned short* wv_b = (unsigned short*)(ws + o_wv);
  unsigned short* wo_b = (unsigned short*)(ws + o_wo);
  unsigned short* w1_b = (unsigned short*)(ws + o_w1);
  unsigned short* w2_b = (unsigned short*)(ws + o_w2);
  unsigned short* h1   = (unsigned short*)(ws + o_h1);
  unsigned short* qb   = (unsigned short*)(ws + o_q);
  unsigned short* kb   = (unsigned short*)(ws + o_k);
  unsigned short* vtb  = (unsigned short*)(ws + o_v);
  float* u_q  = (float*)(ws + o_u);
  float* u_k  = u_q + (size_t)MTOT * RANK;
  float* u_v  = u_k + (size_t)MTOT * RANK;
  unsigned short* ctx = h1;                    // reuse
  float* x2 = (float*)(ws + o_q);              // reuse q+k (32MB)
  unsigned short* h2 = vtb;                    // reuse
  float* u_f1 = u_q;                           // reuse
  float* u_f2 = u_k;                           // reuse
  unsigned short* ffb = (unsigned short*)(ws + o_ff);

  // 1. weights -> bf16
  cvt_bf16<<<512,  256, 0, stream>>>(Wq, wq_b, (D_MODEL * D_MODEL) / 8);
  cvt_bf16<<<512,  256, 0, stream>>>(Wk, wk_b, (D_MODEL * D_MODEL) / 8);
  cvt_bf16<<<512,  256, 0, stream>>>(Wv, wv_b, (D_MODEL * D_MODEL) / 8);
  cvt_bf16<<<512,  256, 0, stream>>>(Wo, wo_b, (D_MODEL * D_MODEL) / 8);
  cvt_bf16<<<2048, 256, 0, stream>>>(W1, w1_b, (D_FF * D_MODEL) / 8);
  cvt_bf16<<<2048, 256, 0, stream>>>(W2, w2_b, (D_FF * D_MODEL) / 8);

  // 2. LN1
  ln_fwd<<<MTOT, 256, 0, stream>>>(x, g1, be1, h1);

  // 3. dynamic u for q,k,v
  dyn_u<D_MODEL><<<MTOT / 16, 256, 0, stream>>>(h1, dyn_q, u_q);
  dyn_u<D_MODEL><<<MTOT / 16, 256, 0, stream>>>(h1, dyn_k, u_k);
  dyn_u<D_MODEL><<<MTOT / 16, 256, 0, stream>>>(h1, dyn_v, u_v);

  // 4. QKV projections (V written pre-transposed)
  dim3 gqkv(D_MODEL / 128, MTOT / 128);
  gemm_bt<D_MODEL, D_MODEL, 0><<<gqkv, 256, 0, stream>>>(h1, wq_b, qb, u_q, Aq, nullptr, nullptr);
  gemm_bt<D_MODEL, D_MODEL, 0><<<gqkv, 256, 0, stream>>>(h1, wk_b, kb, u_k, Ak, nullptr, nullptr);
  gemm_bt<D_MODEL, D_MODEL, 4><<<gqkv, 256, 0, stream>>>(h1, wv_b, vtb, u_v, Av, nullptr, nullptr);

  // 5. attention
  attn_fwd<<<dim3(SEQ / 128, BATCH * NHEADS), 256, 0, stream>>>(qb, kb, vtb, ctx);

  // 6. Wo + residual -> x2 (fp32)
  gemm_bt<D_MODEL, D_MODEL, 1><<<gqkv, 256, 0, stream>>>(ctx, wo_b, x2, nullptr, nullptr, nullptr, x);

  // 7. LN2
  ln_fwd<<<MTOT, 256, 0, stream>>>(x2, g2, be2, h2);

  // 8. u_ff1, FF1 (+bias,+delta,gelu) -> ff bf16
  dyn_u<D_MODEL><<<MTOT / 16, 256, 0, stream>>>(h2, dyn_f1, u_f1);
  gemm_bt<D_FF, D_MODEL, 2><<<dim3(D_FF / 128, MTOT / 128), 256, 0, stream>>>(
      h2, w1_b, ffb, u_f1, A1, b1, nullptr);

  // 9. u_ff2, FF2 (+bias,+delta,+resid) -> out fp32
  dyn_u<D_FF><<<MTOT / 16, 256, 0, stream>>>(ffb, dyn_f2, u_f2);
  gemm_bt<D_MODEL, D_FF, 3><<<gqkv, 256, 0, stream>>>(
      ffb, w2_b, (float*)d_out, u_f2, A2, b2, x2);
}

// Round 3
// 695.220 us; speedup vs baseline: 1.3444x; 1.2451x over previous
//
#include <hip/hip_runtime.h>
#include <math.h>

#define D_MODEL 1024
#define D_FF    4096
#define RANK    8
#define BATCH   4
#define SEQ     2048
#define MTOT    (BATCH*SEQ)
#define NHEADS  16
#define HDIM    64

typedef __attribute__((ext_vector_type(8))) __bf16 bf16x8;
typedef __attribute__((ext_vector_type(4))) float f32x4;
typedef __attribute__((ext_vector_type(8))) unsigned short u16x8;
typedef __attribute__((ext_vector_type(4))) unsigned short u16x4;

__device__ __forceinline__ unsigned short f2bf(float f) {
  union { float f; unsigned int u; } v; v.f = f;
  unsigned int u = v.u;
  u += 0x7fffu + ((u >> 16) & 1u);
  return (unsigned short)(u >> 16);
}
__device__ __forceinline__ float bf2f(unsigned short h) {
  union { unsigned int u; float f; } v; v.u = ((unsigned int)h) << 16;
  return v.f;
}

__device__ __forceinline__ f32x4 mfma16(bf16x8 a, bf16x8 b, f32x4 c) {
  return __builtin_amdgcn_mfma_f32_16x16x32_bf16(a, b, c, 0, 0, 0);
}

#define GLDS(g, l) __builtin_amdgcn_global_load_lds( \
    (const __attribute__((address_space(1))) void*)(g), \
    (__attribute__((address_space(3))) void*)(l), 16, 0, 0)

// ---------------------------------------------------------------- convert f32 -> bf16
__global__ __launch_bounds__(256) void cvt_bf16(const float* __restrict__ in,
                                                unsigned short* __restrict__ out, int n8)
{
  int i = blockIdx.x * 256 + threadIdx.x;
  if (i >= n8) return;
  const float4 a  = *reinterpret_cast<const float4*>(in + (size_t)i * 8);
  const float4 b  = *reinterpret_cast<const float4*>(in + (size_t)i * 8 + 4);
  u16x8 o;
  o[0] = f2bf(a.x); o[1] = f2bf(a.y); o[2] = f2bf(a.z); o[3] = f2bf(a.w);
  o[4] = f2bf(b.x); o[5] = f2bf(b.y); o[6] = f2bf(b.z); o[7] = f2bf(b.w);
  *reinterpret_cast<u16x8*>(out + (size_t)i * 8) = o;
}

// ---------------------------------------------------------------- layernorm (fp32 in, bf16 out)
__global__ __launch_bounds__(256) void ln_fwd(const float* __restrict__ x,
                                              const float* __restrict__ g,
                                              const float* __restrict__ be,
                                              unsigned short* __restrict__ out)
{
  const int row = blockIdx.x;
  const int t = threadIdx.x;
  const float* xr = x + (size_t)row * D_MODEL;
  float4 vv = *reinterpret_cast<const float4*>(xr + t * 4);
  float s  = vv.x + vv.y + vv.z + vv.w;
  float s2 = vv.x * vv.x + vv.y * vv.y + vv.z * vv.z + vv.w * vv.w;
#pragma unroll
  for (int mm = 1; mm < 64; mm <<= 1) { s += __shfl_xor(s, mm); s2 += __shfl_xor(s2, mm); }
  __shared__ float red[8];
  const int w = t >> 6, l = t & 63;
  if (l == 0) { red[w] = s; red[4 + w] = s2; }
  __syncthreads();
  s  = red[0] + red[1] + red[2] + red[3];
  s2 = red[4] + red[5] + red[6] + red[7];
  float mean = s * (1.f / D_MODEL);
  float var  = s2 * (1.f / D_MODEL) - mean * mean;
  float rstd = rsqrtf(var + 1e-5f);
  float4 gv = *reinterpret_cast<const float4*>(g  + t * 4);
  float4 bv = *reinterpret_cast<const float4*>(be + t * 4);
  u16x4 o;
  o[0] = f2bf((vv.x - mean) * rstd * gv.x + bv.x);
  o[1] = f2bf((vv.y - mean) * rstd * gv.y + bv.y);
  o[2] = f2bf((vv.z - mean) * rstd * gv.z + bv.z);
  o[3] = f2bf((vv.w - mean) * rstd * gv.w + bv.w);
  *reinterpret_cast<u16x4*>(out + (size_t)row * D_MODEL + t * 4) = o;
}

// ---------------------------------------------------------------- u[m][r] = sum_i h[m][i]*dyn[b][r][i]
template<int ILEN>
__global__ __launch_bounds__(256) void dyn_u(const unsigned short* __restrict__ hmat,
                                             const float* __restrict__ dyn,
                                             float* __restrict__ u)
{
  const int tid = threadIdx.x, w = tid >> 6, l = tid & 63;
  const int m0 = blockIdx.x * 16 + w * 4;
  const int b = m0 / SEQ;
  const float* dynb = dyn + (size_t)b * RANK * ILEN;
  float acc[4][RANK] = {};
  for (int s = 0; s < ILEN / 64; ++s) {
    const int i = l + s * 64;
    float hv[4];
#pragma unroll
    for (int rr = 0; rr < 4; ++rr) hv[rr] = bf2f(hmat[(size_t)(m0 + rr) * ILEN + i]);
#pragma unroll
    for (int r = 0; r < RANK; ++r) {
      float d = dynb[(size_t)r * ILEN + i];
#pragma unroll
      for (int rr = 0; rr < 4; ++rr) acc[rr][r] += hv[rr] * d;
    }
  }
#pragma unroll
  for (int rr = 0; rr < 4; ++rr)
#pragma unroll
    for (int r = 0; r < RANK; ++r) {
      float a = acc[rr][r];
#pragma unroll
      for (int mm = 1; mm < 64; mm <<= 1) a += __shfl_xor(a, mm);
      if (l == 0) u[(size_t)(m0 + rr) * RANK + r] = a;
    }
}

// ---------------------------------------------------------------- GEMM  C[m,n] = sum_k A[m,k]*B[n,k] (+epilogue)
// BK=64, LDS XOR-swizzled (pre-swizzled global source, swizzled ds_read).
// MODE 1: +resid(fp32), fp32 out (Wo)
// MODE 2: +dyn delta +bias, gelu, bf16 out (FF1)
// MODE 3: +dyn delta +bias +resid, fp32 out (FF2)
// MODE 5: fused QKV: seg=col/1024 -> {Q,K to outp (contiguous), V transposed to outp2}
template<int NDIM, int KDIM, int MODE>
__global__ __launch_bounds__(256) void gemm_bt(const unsigned short* __restrict__ A,
                                               const unsigned short* __restrict__ B,
                                               void* __restrict__ outp,
                                               void* __restrict__ outp2,
                                               const float* __restrict__ uvec,
                                               const float* __restrict__ Ad0,
                                               const float* __restrict__ Ad1,
                                               const float* __restrict__ Ad2,
                                               const float* __restrict__ bias,
                                               const float* __restrict__ resid)
{
  constexpr bool HAS_DYN = (MODE == 2 || MODE == 3 || MODE == 5);
  __shared__ unsigned short sA[128 * 64];
  __shared__ unsigned short sB[128 * 64];
  const int tid = threadIdx.x;
  const int w = tid >> 6, l = tid & 63;

  // bijective XCD swizzle (grids are multiples of 8 blocks)
  constexpr int NBX = NDIM / 128;
  constexpr int NWG = NBX * (MTOT / 128);
  const int bid = blockIdx.y * NBX + blockIdx.x;
  const int sbid = (bid & 7) * (NWG / 8) + (bid >> 3);
  const int tm = (sbid / NBX) * 128, tn = (sbid % NBX) * 128;
  const int wr = w >> 1, wc = w & 1;

  f32x4 acc[4][4] = {};

  // staging: lane l covers source row (l>>3), col-block pre-swizzled
  const int srow = l >> 3;
  const int sc8 = (l & 7) ^ (srow & 7);
  const unsigned short* Ag = A + (size_t)(tm + srow) * KDIM + sc8 * 8;
  const unsigned short* Bg = B + (size_t)(tn + srow) * KDIM + sc8 * 8;

  const int arow = wr * 64 + (l & 15);
  const int bcol = wc * 64 + (l & 15);
  const int kb0 = l >> 4;
  const int swz = l & 7;

  for (int kt = 0; kt < KDIM; kt += 64) {
    __syncthreads();
#pragma unroll
    for (int it = 0; it < 4; ++it) {
      const int r4 = it * 4 + w;
      GLDS(Ag + (size_t)(r4 * 8) * KDIM + kt, sA + r4 * 512);
      GLDS(Bg + (size_t)(r4 * 8) * KDIM + kt, sB + r4 * 512);
    }
    asm volatile("s_waitcnt vmcnt(0)" ::: "memory");
    __syncthreads();

#pragma unroll
    for (int kk = 0; kk < 2; ++kk) {
      bf16x8 af[4], bfv[4];
      const int kphys = ((kk * 4 + kb0) ^ swz) << 3;
#pragma unroll
      for (int i = 0; i < 4; ++i)
        af[i] = *reinterpret_cast<const bf16x8*>(&sA[(arow + i * 16) * 64 + kphys]);
#pragma unroll
      for (int j = 0; j < 4; ++j)
        bfv[j] = *reinterpret_cast<const bf16x8*>(&sB[(bcol + j * 16) * 64 + kphys]);
#pragma unroll
      for (int i = 0; i < 4; ++i)
#pragma unroll
        for (int j = 0; j < 4; ++j)
          acc[i][j] = mfma16(af[i], bfv[j], acc[i][j]);
    }
  }

  const int rbase = tm + wr * 64 + ((l >> 4) << 2);
  const int cbase = tn + wc * 64 + (l & 15);

  const int seg = tn >> 10;  // MODE 5 only (tile never crosses a 1024 boundary)
  const float* Ad = Ad0;
  const float* uv = uvec;
  if constexpr (MODE == 5) {
    Ad = (seg == 0) ? Ad0 : (seg == 1) ? Ad1 : Ad2;
    uv = uvec + (size_t)seg * ((size_t)MTOT * RANK);
  }

#pragma unroll
  for (int i = 0; i < 4; ++i) {
    float uu[4][8];
    if constexpr (HAS_DYN) {
#pragma unroll
      for (int r = 0; r < 4; ++r) {
        const float* up = uv + (size_t)(rbase + i * 16 + r) * RANK;
#pragma unroll
        for (int p = 0; p < 8; ++p) uu[r][p] = up[p];
      }
    }
#pragma unroll
    for (int j = 0; j < 4; ++j) {
      const int col = cbase + j * 16;
      float ad[8];
      if constexpr (HAS_DYN) {
#pragma unroll
        for (int p = 0; p < 8; ++p) ad[p] = Ad[(size_t)col * RANK + p];
      }
      float vv4[4];
#pragma unroll
      for (int r = 0; r < 4; ++r) {
        const int row = rbase + i * 16 + r;
        float v = acc[i][j][r];
        if constexpr (HAS_DYN) {
#pragma unroll
          for (int p = 0; p < 8; ++p) v += uu[r][p] * ad[p];
        }
        if constexpr (MODE == 2) {
          v += bias[col];
          v = 0.5f * v * (1.f + erff(v * 0.70710678118654752f));
        }
        if constexpr (MODE == 1) {
          v += resid[(size_t)row * NDIM + col];
        }
        if constexpr (MODE == 3) {
          v += bias[col] + resid[(size_t)row * NDIM + col];
        }
        vv4[r] = v;
      }
      if constexpr (MODE == 2) {
#pragma unroll
        for (int r = 0; r < 4; ++r)
          ((unsigned short*)outp)[(size_t)(rbase + i * 16 + r) * NDIM + col] = f2bf(vv4[r]);
      } else if constexpr (MODE == 5) {
        const int cl = col & 1023;
        if (seg < 2) {
#pragma unroll
          for (int r = 0; r < 4; ++r)
            ((unsigned short*)outp)[((size_t)seg * MTOT + rbase + i * 16 + r) * D_MODEL + cl] =
                f2bf(vv4[r]);
        } else {
          // vt[b][h][d][t]; 4 consecutive t -> one 8B store
          const int row0 = rbase + i * 16;
          const int bb = row0 >> 11, tt = row0 & (SEQ - 1);
          const int hh = cl >> 6, dd = cl & 63;
          u16x4 o;
          o[0] = f2bf(vv4[0]); o[1] = f2bf(vv4[1]); o[2] = f2bf(vv4[2]); o[3] = f2bf(vv4[3]);
          *reinterpret_cast<u16x4*>(
              &((unsigned short*)outp2)[(((size_t)bb * NHEADS + hh) * HDIM + dd) * SEQ + tt]) = o;
        }
      } else {
#pragma unroll
        for (int r = 0; r < 4; ++r)
          ((float*)outp)[(size_t)(rbase + i * 16 + r) * NDIM + col] = vv4[r];
      }
    }
  }
}

// ---------------------------------------------------------------- flash attention (non-causal)
// KVBLK=128. K [b,t,h*d] staged as [key][d] (swizzled), V pre-transposed
// vt[b][h][d][t] staged as [d][t] (swizzled). sP per-wave 32x64, reused for
// the two 64-key halves (no cross-wave sync needed). XCD-chunked work swizzle.
__global__ __launch_bounds__(256) void attn_fwd(const unsigned short* __restrict__ q,
                                                const unsigned short* __restrict__ k,
                                                const unsigned short* __restrict__ vt,
                                                unsigned short* __restrict__ ctx)
{
  __shared__ unsigned short sK[128 * 64];
  __shared__ unsigned short sV[64 * 128];
  __shared__ unsigned short sP[4][32 * 64];

  const int tid = threadIdx.x, w = tid >> 6, l = tid & 63;
  // grid (16, 64); chunk works so each XCD sees 8 consecutive (b,h) = 4MB KV
  const int lin = blockIdx.y * (SEQ / 128) + blockIdx.x;
  const int W = (lin & 7) * ((BATCH * NHEADS * SEQ / 128) / 8) + (lin >> 3);
  const int bh = W >> 4, b = bh >> 4, hh = bh & 15;
  const int q0 = (W & 15) * 128 + w * 32;
  const size_t base = ((size_t)b * SEQ) * D_MODEL + hh * HDIM;
  const size_t vtbase = (size_t)bh * HDIM * SEQ;

  bf16x8 qf[2][2];
#pragma unroll
  for (int i = 0; i < 2; ++i)
#pragma unroll
    for (int ks = 0; ks < 2; ++ks)
      qf[i][ks] = *reinterpret_cast<const bf16x8*>(
          &q[base + (size_t)(q0 + i * 16 + (l & 15)) * D_MODEL + ks * 32 + (l >> 4) * 8]);

  float mrun[2][4], lrun[2][4];
  f32x4 oacc[2][4] = {};
#pragma unroll
  for (int i = 0; i < 2; ++i)
#pragma unroll
    for (int r = 0; r < 4; ++r) { mrun[i][r] = -3.0e38f; lrun[i][r] = 0.f; }

  // K staging lane constants: row = r4*8 + (l>>3), dest c8 = l&7, src pre-swizzled
  const int krow_l = l >> 3;
  const int kswz = (l & 7) ^ (krow_l & 7);
  const unsigned short* kg = k + base + (size_t)krow_l * D_MODEL + kswz * 8;
  // V staging: row(d) = r4*4 + (l>>4), dest c16 = l&15, row&7 = (w&1)*4 + (l>>4)
  const int vrow_l = l >> 4;
  const int vswz = (l & 15) ^ (((w & 1) * 4 + vrow_l) & 7);
  const unsigned short* vg = vt + vtbase + (size_t)vrow_l * SEQ + vswz * 8;

  const int swz = l & 7;
  const int kb0 = l >> 4;

  for (int kt = 0; kt < SEQ; kt += 128) {
    __syncthreads();
#pragma unroll
    for (int it = 0; it < 4; ++it) {
      const int r4 = it * 4 + w;
      GLDS(kg + (size_t)(kt + r4 * 8) * D_MODEL, sK + r4 * 512);
      GLDS(vg + (size_t)(r4 * 4) * SEQ + kt, sV + r4 * 512);
    }
    asm volatile("s_waitcnt vmcnt(0)" ::: "memory");
    __syncthreads();

    // S = Q K^T  (128 keys = 8 j-blocks)
    f32x4 sacc[2][8] = {};
    __builtin_amdgcn_s_setprio(1);
#pragma unroll
    for (int ks = 0; ks < 2; ++ks) {
#pragma unroll
      for (int j = 0; j < 8; ++j) {
        const int row = j * 16 + (l & 15);
        bf16x8 kf = *reinterpret_cast<const bf16x8*>(
            &sK[row * 64 + (((ks * 4 + kb0) ^ swz) << 3)]);
#pragma unroll
        for (int i = 0; i < 2; ++i) sacc[i][j] = mfma16(qf[i][ks], kf, sacc[i][j]);
      }
    }
    __builtin_amdgcn_s_setprio(0);

    // online softmax over 128 keys; pack half A (j=0..3), save half B in regs
    float pr[2][4][4];
#pragma unroll
    for (int i = 0; i < 2; ++i) {
#pragma unroll
      for (int r = 0; r < 4; ++r) {
        float sv[8];
#pragma unroll
        for (int j = 0; j < 8; ++j) sv[j] = sacc[i][j][r] * 0.125f;
        float mx = fmaxf(fmaxf(fmaxf(sv[0], sv[1]), fmaxf(sv[2], sv[3])),
                         fmaxf(fmaxf(sv[4], sv[5]), fmaxf(sv[6], sv[7])));
#pragma unroll
        for (int mm = 1; mm < 16; mm <<= 1) mx = fmaxf(mx, __shfl_xor(mx, mm, 16));
        const float mnew = fmaxf(mrun[i][r], mx);
        const float alpha = __expf(mrun[i][r] - mnew);
        mrun[i][r] = mnew;
        float p[8], ps = 0.f;
#pragma unroll
        for (int j = 0; j < 8; ++j) { p[j] = __expf(sv[j] - mnew); ps += p[j]; }
#pragma unroll
        for (int mm = 1; mm < 16; mm <<= 1) ps += __shfl_xor(ps, mm, 16);
        lrun[i][r] = lrun[i][r] * alpha + ps;
        const int prow = i * 16 + ((l >> 4) << 2) + r;
        const int pswz = prow & 7;
        unsigned short* pb = &sP[w][prow * 64];
        const int chi = (l & 15) >> 3, clo = l & 7;
        pb[(((0 + chi) ^ pswz) << 3) + clo] = f2bf(p[0]);
        pb[(((2 + chi) ^ pswz) << 3) + clo] = f2bf(p[1]);
        pb[(((4 + chi) ^ pswz) << 3) + clo] = f2bf(p[2]);
        pb[(((6 + chi) ^ pswz) << 3) + clo] = f2bf(p[3]);
#pragma unroll
        for (int jj = 0; jj < 4; ++jj) pr[i][r][jj] = p[4 + jj];
#pragma unroll
        for (int j = 0; j < 4; ++j) oacc[i][j][r] *= alpha;
      }
    }

    // O += P V, half A (keys kt..kt+63)
    __builtin_amdgcn_s_setprio(1);
#pragma unroll
    for (int ks = 0; ks < 2; ++ks) {
      bf16x8 pf[2];
#pragma unroll
      for (int i = 0; i < 2; ++i) {
        const int prw = i * 16 + (l & 15);
        pf[i] = *reinterpret_cast<const bf16x8*>(
            &sP[w][prw * 64 + (((ks * 4 + kb0) ^ swz) << 3)]);
      }
#pragma unroll
      for (int j = 0; j < 4; ++j) {
        const int row = j * 16 + (l & 15);
        bf16x8 vf = *reinterpret_cast<const bf16x8*>(
            &sV[row * 128 + (((ks * 4 + kb0) ^ swz) << 3)]);
#pragma unroll
        for (int i = 0; i < 2; ++i) oacc[i][j] = mfma16(pf[i], vf, oacc[i][j]);
      }
    }
    __builtin_amdgcn_s_setprio(0);

    // pack half B (keys kt+64..kt+127) into same sP
#pragma unroll
    for (int i = 0; i < 2; ++i) {
#pragma unroll
      for (int r = 0; r < 4; ++r) {
        const int prow = i * 16 + ((l >> 4) << 2) + r;
        const int pswz = prow & 7;
        unsigned short* pb = &sP[w][prow * 64];
        const int chi = (l & 15) >> 3, clo = l & 7;
        pb[(((0 + chi) ^ pswz) << 3) + clo] = f2bf(pr[i][r][0]);
        pb[(((2 + chi) ^ pswz) << 3) + clo] = f2bf(pr[i][r][1]);
        pb[(((4 + chi) ^ pswz) << 3) + clo] = f2bf(pr[i][r][2]);
        pb[(((6 + chi) ^ pswz) << 3) + clo] = f2bf(pr[i][r][3]);
      }
    }

    // O += P V, half B
    __builtin_amdgcn_s_setprio(1);
#pragma unroll
    for (int ks = 0; ks < 2; ++ks) {
      bf16x8 pf[2];
#pragma unroll
      for (int i = 0; i < 2; ++i) {
        const int prw = i * 16 + (l & 15);
        pf[i] = *reinterpret_cast<const bf16x8*>(
            &sP[w][prw * 64 + (((ks * 4 + kb0) ^ swz) << 3)]);
      }
#pragma unroll
      for (int j = 0; j < 4; ++j) {
        const int row = j * 16 + (l & 15);
        bf16x8 vf = *reinterpret_cast<const bf16x8*>(
            &sV[row * 128 + (((8 + ks * 4 + kb0) ^ swz) << 3)]);
#pragma unroll
        for (int i = 0; i < 2; ++i) oacc[i][j] = mfma16(pf[i], vf, oacc[i][j]);
      }
    }
    __builtin_amdgcn_s_setprio(0);
  }

#pragma unroll
  for (int i = 0; i < 2; ++i)
#pragma unroll
    for (int r = 0; r < 4; ++r) {
      float inv = 1.f / lrun[i][r];
      int row = q0 + i * 16 + ((l >> 4) << 2) + r;
#pragma unroll
      for (int j = 0; j < 4; ++j)
        ctx[base + (size_t)row * D_MODEL + j * 16 + (l & 15)] = f2bf(oacc[i][j][r] * inv);
    }
}

// ---------------------------------------------------------------- launch
extern "C" void kernel_launch(void* const* d_in, const int* in_sizes, int n_in,
                              void* d_out, int out_size, void* d_ws, size_t ws_size,
                              hipStream_t stream)
{
  (void)in_sizes; (void)n_in; (void)out_size; (void)ws_size;
  const float* x      = (const float*)d_in[0];
  const float* dyn_q  = (const float*)d_in[1];
  const float* dyn_k  = (const float*)d_in[2];
  const float* dyn_v  = (const float*)d_in[3];
  const float* dyn_f1 = (const float*)d_in[4];
  const float* dyn_f2 = (const float*)d_in[5];
  const float* Wq = (const float*)d_in[6];
  const float* Aq = (const float*)d_in[7];
  const float* Wk = (const float*)d_in[8];
  const float* Ak = (const float*)d_in[9];
  const float* Wv = (const float*)d_in[10];
  const float* Av = (const float*)d_in[11];
  const float* Wo = (const float*)d_in[12];
  const float* W1 = (const float*)d_in[13];
  const float* b1 = (const float*)d_in[14];
  const float* A1 = (const float*)d_in[15];
  const float* W2 = (const float*)d_in[16];
  const float* b2 = (const float*)d_in[17];
  const float* A2 = (const float*)d_in[18];
  const float* g1 = (const float*)d_in[19];
  const float* be1 = (const float*)d_in[20];
  const float* g2 = (const float*)d_in[21];
  const float* be2 = (const float*)d_in[22];

  char* ws = (char*)d_ws;
  size_t o = 0;
  auto take = [&](size_t b) { size_t r = o; o += (b + 255) & ~(size_t)255; return r; };
  const size_t o_wq = take((size_t)D_MODEL * D_MODEL * 2);  // wq,wk,wv contiguous (2MB each)
  const size_t o_wk = take((size_t)D_MODEL * D_MODEL * 2);
  const size_t o_wv = take((size_t)D_MODEL * D_MODEL * 2);
  const size_t o_wo = take((size_t)D_MODEL * D_MODEL * 2);
  const size_t o_w1 = take((size_t)D_FF * D_MODEL * 2);
  const size_t o_w2 = take((size_t)D_FF * D_MODEL * 2);
  const size_t o_h1 = take((size_t)MTOT * D_MODEL * 2);   // later reused as ctx
  const size_t o_q  = take((size_t)MTOT * D_MODEL * 2);   // q,k contiguous; later x2
  const size_t o_k  = take((size_t)MTOT * D_MODEL * 2);
  const size_t o_v  = take((size_t)MTOT * D_MODEL * 2);   // vt; later reused as h2
  const size_t o_u  = take((size_t)MTOT * RANK * 4 * 3);  // u_q,u_k,u_v contiguous
  const size_t o_ff = take((size_t)MTOT * D_FF * 2);

  unsigned short* wq_b = (unsigned short*)(ws + o_wq);
  unsigned short* wk_b = (unsigned short*)(ws + o_wk);
  unsigned short* wv_b = (unsigned short*)(ws + o_wv);
  unsigned short* wo_b = (unsigned short*)(ws + o_wo);
  unsigned short* w1_b = (unsigned short*)(ws + o_w1);
  unsigned short* w2_b = (unsigned short*)(ws + o_w2);
  unsigned short* h1   = (unsigned short*)(ws + o_h1);
  unsigned short* qb   = (unsigned short*)(ws + o_q);
  unsigned short* vtb  = (unsigned short*)(ws + o_v);
  float* u_q  = (float*)(ws + o_u);
  float* u_k  = u_q + (size_t)MTOT * RANK;
  float* u_v  = u_k + (size_t)MTOT * RANK;
  unsigned short* ctx = h1;                    // reuse
  float* x2 = (float*)(ws + o_q);              // reuse q+k (32MB)
  unsigned short* h2 = vtb;                    // reuse
  float* u_f1 = u_q;                           // reuse
  float* u_f2 = u_k;                           // reuse
  unsigned short* ffb = (unsigned short*)(ws + o_ff);

  // 1. weights -> bf16
  cvt_bf16<<<512,  256, 0, stream>>>(Wq, wq_b, (D_MODEL * D_MODEL) / 8);
  cvt_bf16<<<512,  256, 0, stream>>>(Wk, wk_b, (D_MODEL * D_MODEL) / 8);
  cvt_bf16<<<512,  256, 0, stream>>>(Wv, wv_b, (D_MODEL * D_MODEL) / 8);
  cvt_bf16<<<512,  256, 0, stream>>>(Wo, wo_b, (D_MODEL * D_MODEL) / 8);
  cvt_bf16<<<2048, 256, 0, stream>>>(W1, w1_b, (D_FF * D_MODEL) / 8);
  cvt_bf16<<<2048, 256, 0, stream>>>(W2, w2_b, (D_FF * D_MODEL) / 8);

  // 2. LN1
  ln_fwd<<<MTOT, 256, 0, stream>>>(x, g1, be1, h1);

  // 3. dynamic u for q,k,v
  dyn_u<D_MODEL><<<MTOT / 16, 256, 0, stream>>>(h1, dyn_q, u_q);
  dyn_u<D_MODEL><<<MTOT / 16, 256, 0, stream>>>(h1, dyn_k, u_k);
  dyn_u<D_MODEL><<<MTOT / 16, 256, 0, stream>>>(h1, dyn_v, u_v);

  // 4. fused QKV projection (V written pre-transposed)
  gemm_bt<3 * D_MODEL, D_MODEL, 5><<<dim3(3 * D_MODEL / 128, MTOT / 128), 256, 0, stream>>>(
      h1, wq_b, qb, vtb, u_q, Aq, Ak, Av, nullptr, nullptr);

  // 5. attention
  attn_fwd<<<dim3(SEQ / 128, BATCH * NHEADS), 256, 0, stream>>>(
      qb, qb + (size_t)MTOT * D_MODEL, vtb, ctx);

  // 6. Wo + residual -> x2 (fp32)
  gemm_bt<D_MODEL, D_MODEL, 1><<<dim3(D_MODEL / 128, MTOT / 128), 256, 0, stream>>>(
      ctx, wo_b, x2, nullptr, nullptr, nullptr, nullptr, nullptr, nullptr, x);

  // 7. LN2
  ln_fwd<<<MTOT, 256, 0, stream>>>(x2, g2, be2, h2);

  // 8. u_ff1, FF1 (+bias,+delta,gelu) -> ff bf16
  dyn_u<D_MODEL><<<MTOT / 16, 256, 0, stream>>>(h2, dyn_f1, u_f1);
  gemm_bt<D_FF, D_MODEL, 2><<<dim3(D_FF / 128, MTOT / 128), 256, 0, stream>>>(
      h2, w1_b, ffb, nullptr, u_f1, A1, nullptr, nullptr, b1, nullptr);

  // 9. u_ff2, FF2 (+bias,+delta,+resid) -> out fp32
  dyn_u<D_FF><<<MTOT / 16, 256, 0, stream>>>(ffb, dyn_f2, u_f2);
  gemm_bt<D_MODEL, D_FF, 3><<<dim3(D_MODEL / 128, MTOT / 128), 256, 0, stream>>>(
      ffb, w2_b, (float*)d_out, nullptr, u_f2, A2, nullptr, nullptr, b2, x2);
}